// Round 2
// baseline (147.785 us; speedup 1.0000x reference)
//
#include <hip/hip_runtime.h>
#include <stdint.h>

#pragma clang fp contract(off)

#define B_ 2
#define P_ 512
#define C_ 21
#define CF 20            // foreground classes
#define DET 100
#define SCORE_THRESH 0.05f
#define NMS_THR 0.5f
#define BBOX_CLIP 4.135166556742356f   // log(1000/16)
#define NC (CF * DET)    // 2000 candidates per image
#define CH 4096          // pair-chunk size (per fused-block iteration)

typedef unsigned long long u64;
typedef unsigned int u32;

__device__ __forceinline__ u32 f2o(float f) {
  u32 u = __float_as_uint(f);
  return (u & 0x80000000u) ? ~u : (u | 0x80000000u);
}

// ---------------------------------------------------------------------------
// exact convex quad-quad intersection area — register-resident, bit-identical
// float op order vs reference (fp contract off). Clips quad q by edges of r.
// ---------------------------------------------------------------------------
__device__ __forceinline__ float inter_area_reg(const float qx[4], const float qy[4],
                                                const float rx[4], const float ry[4]) {
  float px_[8], py_[8];
  #pragma unroll
  for (int t = 0; t < 8; ++t) { px_[t] = (t < 4) ? qx[t] : 0.f; py_[t] = (t < 4) ? qy[t] : 0.f; }
  int n = 4;
  #pragma unroll
  for (int e = 0; e < 4; ++e) {
    float a0 = rx[e], a1 = ry[e];
    float b0 = rx[(e + 1) & 3], b1 = ry[(e + 1) & 3];
    float dx = b0 - a0, dy = b1 - a1;
    float ox_[8], oy_[8];
    #pragma unroll
    for (int t = 0; t < 8; ++t) { ox_[t] = 0.f; oy_[t] = 0.f; }
    float cr[8];
    #pragma unroll
    for (int t = 0; t < 8; ++t) cr[t] = dx * (py_[t] - a1) - dy * (px_[t] - a0);
    int m = 0;
    int nn = (n > 1) ? n : 1;
    #pragma unroll
    for (int t = 0; t < 8; ++t) {
      bool act = t < n;
      float sx = px_[t], sy = py_[t];
      float ex, ey, ce;
      if (t == 7) { ex = px_[0]; ey = py_[0]; ce = cr[0]; }
      else {
        bool wrap = (t + 1 == nn);
        ex = wrap ? px_[0] : px_[t + 1];
        ey = wrap ? py_[0] : py_[t + 1];
        ce = wrap ? cr[0] : cr[t + 1];
      }
      float cs = cr[t];
      float denom = cs - ce;
      float dn = (fabsf(denom) > 1e-12f) ? denom : 1e-12f;
      float tt = cs / dn;
      float ipx = sx + tt * (ex - sx);
      float ipy = sy + tt * (ey - sy);
      bool s_in = cs >= 0.f, e_in = ce >= 0.f;
      bool app1 = act && (s_in != e_in);
      #pragma unroll
      for (int s2 = 0; s2 < 8; ++s2) {
        bool wr = app1 && (m == s2);
        ox_[s2] = wr ? ipx : ox_[s2];
        oy_[s2] = wr ? ipy : oy_[s2];
      }
      m += app1 ? 1 : 0;
      bool app2 = act && e_in;
      #pragma unroll
      for (int s2 = 0; s2 < 8; ++s2) {
        bool wr = app2 && (m == s2);
        ox_[s2] = wr ? ex : ox_[s2];
        oy_[s2] = wr ? ey : oy_[s2];
      }
      m += app2 ? 1 : 0;
    }
    n = m;
    #pragma unroll
    for (int t = 0; t < 8; ++t) { px_[t] = ox_[t]; py_[t] = oy_[t]; }
  }
  int nn = (n > 1) ? n : 1;
  float s = 0.f;
  #pragma unroll
  for (int t = 0; t < 8; ++t) {
    if (t < n) {
      float nx_x, nx_y;
      if (t == 7) { nx_x = px_[0]; nx_y = py_[0]; }
      else {
        bool wrap = (t + 1 == nn);
        nx_x = wrap ? px_[0] : px_[t + 1];
        nx_y = wrap ? py_[0] : py_[t + 1];
      }
      s += px_[t] * nx_y - nx_x * py_[t];
    }
  }
  float area = 0.5f * fabsf(s);
  return (n >= 3) ? area : 0.f;
}

// ---------------------------------------------------------------------------
// Fused per-group kernel: decode + rank-sort + AABB-filtered exact-IoU pair
// phase + serial greedy NMS + emit — everything LDS-resident, one block per
// (image,class) group. No global intermediates except cand/rec for K4.
//   LDS: ckey 4.2K | sorted arrays ~45K | sup bitmask 32K | pair queue 16K
//   ≈ 92 KB -> 1 block/CU (grid=40 on 256 CUs, so no occupancy loss).
// ---------------------------------------------------------------------------
__global__ void __launch_bounds__(512)
fused_kernel(const float* __restrict__ logits,
             const float* __restrict__ breg,
             const float* __restrict__ rrects,
             u64* __restrict__ cand, float* __restrict__ rec) {
  int g = blockIdx.x;
  int b = g / CF, cf = g % CF, c = cf + 1;
  int tid = threadIdx.x;
  int w = tid >> 6, lane = tid & 63;

  __shared__ u64 ckey[P_ + 8];     // compacted valid keys + zero pad
  __shared__ int wcnt[8];
  __shared__ float scs[P_];        // sorted scores
  __shared__ float4 ptsX[P_];      // sorted corner x
  __shared__ float4 ptsY[P_];      // sorted corner y
  __shared__ float4 aabb[P_];      // sorted unclipped aabb
  __shared__ float pr5[P_ * 5];    // sorted proposals
  __shared__ float areaL[P_];      // sorted area
  __shared__ u32 lsup[P_ * 16];    // suppression bitmask rows (u32 words)
  __shared__ u32 q[CH];            // surviving-pair queue for current chunk
  __shared__ int qn;
  __shared__ u32 skeep[16];

  // ---- phase A: decode 1 proposal/thread into registers ----
  int p = tid;
  int n = b * P_ + p;
  const float* lgp = logits + n * C_;
  float lg[C_];
  #pragma unroll
  for (int k = 0; k < C_; ++k) lg[k] = lgp[k];
  float mx = lg[0];
  #pragma unroll
  for (int k = 1; k < C_; ++k) mx = fmaxf(mx, lg[k]);
  float den = 0.f, num = 0.f;
  #pragma unroll
  for (int k = 0; k < C_; ++k) {
    float ex = expf(lg[k] - mx);   // same input bits as expf(lg[c]-mx)
    den += ex;
    num = (k == c) ? ex : num;
  }
  float sc = num / den;

  const float* d = breg + n * (C_ * 5) + c * 5;
  float dx = d[0] / 10.0f, dy = d[1] / 10.0f;
  float dw = d[2] / 5.0f, dh = d[3] / 5.0f, da = d[4] / 3.0f;
  dw = fminf(dw, BBOX_CLIP);
  dh = fminf(dh, BBOX_CLIP);
  const float* an = rrects + n * 5;
  float px = dx * an[2] + an[0];
  float py = dy * an[3] + an[1];
  float pw = expf(dw) * an[2];
  float ph = expf(dh) * an[3];
  float pa = da * 57.29577951308232f + an[4];
  float area = pw * ph;

  float t = pa * 0.017453292519943295f;
  float cs = cosf(t), sn = sinf(t);
  float hx = pw * 0.5f, hy = ph * 0.5f;
  float ox[4] = {-hx, hx, hx, -hx};
  float oy[4] = {-hy, -hy, hy, hy};
  float X[4], Y[4];
  float minx = 1e30f, miny = 1e30f, maxx = -1e30f, maxy = -1e30f;
  #pragma unroll
  for (int qq = 0; qq < 4; ++qq) {
    float x = px + cs * ox[qq] - sn * oy[qq];
    float y = py + sn * ox[qq] + cs * oy[qq];
    X[qq] = x; Y[qq] = y;
    minx = fminf(minx, x); maxx = fmaxf(maxx, x);
    miny = fminf(miny, y); maxy = fmaxf(maxy, y);
  }

  bool valid = sc > SCORE_THRESH;
  float v = valid ? sc : -1.0f;
  u64 key = ((u64)f2o(v) << 32) | (u32)(~(u32)p);

  u64 m = __ballot(valid);
  if (lane == 0) wcnt[w] = __popcll(m);

  // zero suppression bitmask while waiting at the barrier
  for (int z = tid; z < P_ * 16; z += 512) lsup[z] = 0u;
  __syncthreads();

  // ---- phase B: per-wave prefix + valid-key compaction ----
  int V = 0, myb = 0;
  #pragma unroll
  for (int si = 0; si < 8; ++si) {
    int cnti = wcnt[si];
    myb += (si < w) ? cnti : 0;
    V += cnti;
  }
  int slot = myb + __popcll(m & ((1ull << lane) - 1ull));
  if (valid) ckey[slot] = key;
  if (tid < 8) ckey[V + tid] = 0ull;   // pad: 0 never > any valid key
  __syncthreads();

  // ---- phase C: rank among valid keys (4-way unrolled), scatter to LDS ----
  int Vr = (V + 3) & ~3;
  int r = 0;
  for (int s = 0; s < Vr; s += 4) {
    u64 a0 = ckey[s], a1 = ckey[s + 1], a2 = ckey[s + 2], a3 = ckey[s + 3];
    r += (a0 > key) ? 1 : 0;
    r += (a1 > key) ? 1 : 0;
    r += (a2 > key) ? 1 : 0;
    r += (a3 > key) ? 1 : 0;
  }
  if (valid) {
    scs[r] = v;
    ptsX[r] = make_float4(X[0], X[1], X[2], X[3]);
    ptsY[r] = make_float4(Y[0], Y[1], Y[2], Y[3]);
    aabb[r] = make_float4(minx, miny, maxx, maxy);
    pr5[r * 5 + 0] = px; pr5[r * 5 + 1] = py;
    pr5[r * 5 + 2] = pw; pr5[r * 5 + 3] = ph;
    pr5[r * 5 + 4] = pa;
    areaL[r] = area;
  }
  __syncthreads();

  // ---- phase D: pair phase, chunked over triangular pair space ----
  int Tp = V * (V - 1) / 2;
  for (int base = 0; base < Tp; base += CH) {
    if (tid == 0) qn = 0;
    __syncthreads();
    #pragma unroll
    for (int tchunk = 0; tchunk < CH / 512; ++tchunk) {
      int kk = base + tchunk * 512 + tid;
      if (kk < Tp) {
        float kf = (float)kk;
        int i = (int)((1.0f + sqrtf(1.0f + 8.0f * kf)) * 0.5f);
        while (i * (i - 1) / 2 > kk) --i;
        while ((i + 1) * i / 2 <= kk) ++i;
        int j = kk - i * (i - 1) / 2;
        float4 bi = aabb[i];
        float4 bj = aabb[j];
        bool ov = (bi.x <= bj.z) && (bj.x <= bi.z) && (bi.y <= bj.w) && (bj.y <= bi.w);
        if (ov) {
          int s = atomicAdd(&qn, 1);
          q[s] = (u32)((i << 9) | j);
        }
      }
    }
    __syncthreads();
    int nq = qn;
    for (int s = tid; s < nq; s += 512) {
      u32 pk = q[s];
      int i = (int)(pk >> 9), j = (int)(pk & 511);
      float4 ax = ptsX[i], ay = ptsY[i];
      float4 bx = ptsX[j], by = ptsY[j];
      float qx[4] = {ax.x, ax.y, ax.z, ax.w};
      float qy[4] = {ay.x, ay.y, ay.z, ay.w};
      float rx[4] = {bx.x, bx.y, bx.z, bx.w};
      float ry[4] = {by.x, by.y, by.z, by.w};
      float ai = areaL[i];
      float aj = areaL[j];
      // reference iou[i][j]: clip quad i by edges of quad j
      float inter = inter_area_reg(qx, qy, rx, ry);
      float iou = inter / (((ai + aj) - inter) + 1e-8f);
      if (iou > NMS_THR)
        atomicOr(&lsup[i * 16 + (j >> 5)], 1u << (j & 31));
    }
    __syncthreads();
  }

  // ---- phase E: serial greedy on wave 0 (prefetched LDS rows) ----
  if (tid < 64) {
    u32 keepw = 0;
    u32 cur = (tid < 16 && V > 0) ? lsup[tid] : 0u;
    for (int i = 0; i < V; ++i) {
      u32 nxt = (tid < 16 && (i + 1) < V) ? lsup[(i + 1) * 16 + tid] : 0u;
      bool supd = __any((cur & keepw) != 0u);
      if (!supd && tid == (i >> 5)) keepw |= 1u << (i & 31);
      cur = nxt;
    }
    if (tid < 16) skeep[tid] = keepw;
  }
  __syncthreads();

  // ---- phase F: emit kept entries (first DET) + zero-fill tail ----
  int tot = 0;
  #pragma unroll
  for (int t2 = 0; t2 < 16; ++t2) tot += __popc(skeep[t2]);
  int rr_i = tid;
  if (rr_i < V) {
    if ((skeep[rr_i >> 5] >> (rr_i & 31)) & 1u) {
      int oslot = __popc(skeep[rr_i >> 5] & ((1u << (rr_i & 31)) - 1u));
      for (int t2 = 0; t2 < (rr_i >> 5); ++t2) oslot += __popc(skeep[t2]);
      if (oslot < DET) {
        float sv = scs[rr_i];
        int flat = cf * P_ + rr_i;
        cand[g * DET + oslot] = ((u64)f2o(sv) << 32) | (u32)(~(u32)flat);
        float* rrp = rec + (size_t)(g * DET + oslot) * 12;
        float4 ab4 = aabb[rr_i];
        rrp[0] = fminf(fmaxf(ab4.x, 0.f), 1023.0f);
        rrp[1] = fminf(fmaxf(ab4.y, 0.f), 799.0f);
        rrp[2] = fminf(fmaxf(ab4.z, 0.f), 1023.0f);
        rrp[3] = fminf(fmaxf(ab4.w, 0.f), 799.0f);
        rrp[4] = pr5[rr_i * 5 + 0]; rrp[5] = pr5[rr_i * 5 + 1];
        rrp[6] = pr5[rr_i * 5 + 2]; rrp[7] = pr5[rr_i * 5 + 3];
        rrp[8] = pr5[rr_i * 5 + 4];
        rrp[9] = sv;
        rrp[10] = (float)(cf + 1);
        rrp[11] = 0.f;
      }
    }
  }
  int fill = tot < DET ? tot : DET;
  for (int s = fill + tid; s < DET; s += 512) cand[g * DET + s] = 0ull;
}

// ---------------------------------------------------------------------------
// K4 (rank): per-image top-100 by rank (binary search per sorted group list);
// scatter record to row `rank`; zero-fill unused rows in-kernel (no memset).
// out layout: bb[2,100,4] | rr[2,100,5] | sc[2,100] | lab[2,100] (all f32)
// ---------------------------------------------------------------------------
__global__ void rank_kernel(const u64* __restrict__ cand, const float* __restrict__ rec,
                            float* __restrict__ out) {
  int b = blockIdx.y;
  int tid = threadIdx.x;
  __shared__ u64 lc[NC];
  __shared__ int ncand;
  if (tid == 0) ncand = 0;
  __syncthreads();
  int nz = 0;
  for (int i = tid; i < NC; i += 256) {
    u64 v = cand[b * NC + i];
    lc[i] = v;
    nz += (v != 0ull) ? 1 : 0;
  }
  if (nz > 0) atomicAdd(&ncand, nz);
  __syncthreads();
  int ci = blockIdx.x * 256 + tid;
  if (ci >= NC) return;
  // zero-fill unused rows from block 0
  if (blockIdx.x == 0 && tid < DET && tid >= ncand) {
    int o_bb = (b * DET + tid) * 4;
    int o_rr = B_ * DET * 4 + (b * DET + tid) * 5;
    int o_sc = B_ * DET * 9 + b * DET + tid;
    int o_lab = B_ * DET * 10 + b * DET + tid;
    out[o_bb + 0] = 0.f; out[o_bb + 1] = 0.f; out[o_bb + 2] = 0.f; out[o_bb + 3] = 0.f;
    out[o_rr + 0] = 0.f; out[o_rr + 1] = 0.f; out[o_rr + 2] = 0.f;
    out[o_rr + 3] = 0.f; out[o_rr + 4] = 0.f;
    out[o_sc] = 0.f;
    out[o_lab] = 0.f;
  }
  u64 k = lc[ci];
  if (k == 0ull) return;
  int rank = 0;
  #pragma unroll
  for (int gp = 0; gp < CF; ++gp) {
    int lo = 0, hi = DET;
    while (lo < hi) {            // first idx with lc[gp*DET+idx] <= k (desc list)
      int mid = (lo + hi) >> 1;
      if (lc[gp * DET + mid] > k) lo = mid + 1; else hi = mid;
    }
    rank += lo;
  }
  if (rank >= DET) return;
  const float* rr = rec + (size_t)(b * NC + ci) * 12;
  int o_bb = (b * DET + rank) * 4;
  int o_rr = B_ * DET * 4 + (b * DET + rank) * 5;
  int o_sc = B_ * DET * 9 + b * DET + rank;
  int o_lab = B_ * DET * 10 + b * DET + rank;
  out[o_bb + 0] = rr[0]; out[o_bb + 1] = rr[1];
  out[o_bb + 2] = rr[2]; out[o_bb + 3] = rr[3];
  out[o_rr + 0] = rr[4]; out[o_rr + 1] = rr[5]; out[o_rr + 2] = rr[6];
  out[o_rr + 3] = rr[7]; out[o_rr + 4] = rr[8];
  out[o_sc] = rr[9];
  out[o_lab] = rr[10];
}

// ---------------------------------------------------------------------------
extern "C" void kernel_launch(void* const* d_in, const int* in_sizes, int n_in,
                              void* d_out, int out_size, void* d_ws, size_t ws_size,
                              hipStream_t stream) {
  const float* logits = (const float*)d_in[0];
  const float* breg   = (const float*)d_in[1];
  const float* rrects = (const float*)d_in[2];
  float* out = (float*)d_out;

  const int G = B_ * CF;
  u64*   cand = (u64*)d_ws;                          // G*DET u64  = 32 KB
  float* rec  = (float*)(cand + G * DET);            // G*DET*12 f32 = 192 KB

  fused_kernel<<<G, 512, 0, stream>>>(logits, breg, rrects, cand, rec);
  rank_kernel<<<dim3((NC + 255) / 256, B_), 256, 0, stream>>>(cand, rec, out);
}

// Round 3
// 127.727 us; speedup vs baseline: 1.1570x; 1.1570x over previous
//
#include <hip/hip_runtime.h>
#include <stdint.h>

#pragma clang fp contract(off)

#define B_ 2
#define P_ 512
#define C_ 21
#define CF 20            // foreground classes
#define DET 100
#define SCORE_THRESH 0.05f
#define NMS_THR 0.5f
#define BBOX_CLIP 4.135166556742356f   // log(1000/16)
#define NC (CF * DET)    // 2000 candidates per image

typedef unsigned long long u64;
typedef unsigned int u32;

__device__ __forceinline__ u32 f2o(float f) {
  u32 u = __float_as_uint(f);
  return (u & 0x80000000u) ? ~u : (u | 0x80000000u);
}

// ---------------------------------------------------------------------------
// K1 (prep): per-(image,class) decode + rank-scatter sort.
// 512 thr (1 proposal/thread, 8 waves for latency hiding), valid-key
// compaction so the rank loop runs over V (~150) instead of P (512).
// ---------------------------------------------------------------------------
__global__ void __launch_bounds__(512)
prep_kernel(const float* __restrict__ logits,
            const float* __restrict__ breg,
            const float* __restrict__ rrects,
            float* __restrict__ scsS,   // [G*P] sorted scores (valid prefix)
            float* __restrict__ ptsS,   // [G*P][8] sorted pts
            float* __restrict__ aabbS,  // [G*P][4] sorted unclipped aabb
            float* __restrict__ pr5S,   // [G*P][5] sorted proposals
            float* __restrict__ areaS,  // [G*P] sorted area
            int* __restrict__ gV,
            u64* __restrict__ sup) {
  int g = blockIdx.x;
  int b = g / CF, cf = g % CF, c = cf + 1;
  int tid = threadIdx.x;
  int w = tid >> 6, lane = tid & 63;

  __shared__ u64 ckey[P_ + 8];   // compacted valid keys + zero pad
  __shared__ int wcnt[8];

  // ---- decode 1 proposal/thread, keep data in registers ----
  int p = tid;
  int n = b * P_ + p;
  const float* lgp = logits + n * C_;
  float lg[C_];
  #pragma unroll
  for (int k = 0; k < C_; ++k) lg[k] = lgp[k];
  float mx = lg[0];
  #pragma unroll
  for (int k = 1; k < C_; ++k) mx = fmaxf(mx, lg[k]);
  float den = 0.f, num = 0.f;
  #pragma unroll
  for (int k = 0; k < C_; ++k) {
    float ex = expf(lg[k] - mx);   // same input bits as expf(lg[c]-mx)
    den += ex;
    num = (k == c) ? ex : num;
  }
  float sc = num / den;

  const float* d = breg + n * (C_ * 5) + c * 5;
  float dx = d[0] / 10.0f, dy = d[1] / 10.0f;
  float dw = d[2] / 5.0f, dh = d[3] / 5.0f, da = d[4] / 3.0f;
  dw = fminf(dw, BBOX_CLIP);
  dh = fminf(dh, BBOX_CLIP);
  const float* an = rrects + n * 5;
  float px = dx * an[2] + an[0];
  float py = dy * an[3] + an[1];
  float pw = expf(dw) * an[2];
  float ph = expf(dh) * an[3];
  float pa = da * 57.29577951308232f + an[4];
  float area = pw * ph;

  float t = pa * 0.017453292519943295f;
  float cs = cosf(t), sn = sinf(t);
  float hx = pw * 0.5f, hy = ph * 0.5f;
  float ox[4] = {-hx, hx, hx, -hx};
  float oy[4] = {-hy, -hy, hy, hy};
  float X[4], Y[4];
  float minx = 1e30f, miny = 1e30f, maxx = -1e30f, maxy = -1e30f;
  #pragma unroll
  for (int q = 0; q < 4; ++q) {
    float x = px + cs * ox[q] - sn * oy[q];
    float y = py + sn * ox[q] + cs * oy[q];
    X[q] = x; Y[q] = y;
    minx = fminf(minx, x); maxx = fmaxf(maxx, x);
    miny = fminf(miny, y); maxy = fmaxf(maxy, y);
  }

  bool valid = sc > SCORE_THRESH;
  float v = valid ? sc : -1.0f;
  u64 key = ((u64)f2o(v) << 32) | (u32)(~(u32)p);

  u64 m = __ballot(valid);
  if (lane == 0) wcnt[w] = __popcll(m);

  // zero this group's suppression slice while waiting at the barrier
  for (int z = tid; z < P_ * 8; z += 512) sup[(size_t)g * P_ * 8 + z] = 0ull;
  __syncthreads();

  // ---- per-wave prefix over 8 segment counts (broadcast LDS reads) ----
  int V = 0, myb = 0;
  #pragma unroll
  for (int si = 0; si < 8; ++si) {
    int cnti = wcnt[si];
    myb += (si < w) ? cnti : 0;
    V += cnti;
  }
  int slot = myb + __popcll(m & ((1ull << lane) - 1ull));
  if (valid) ckey[slot] = key;
  if (tid < 8) ckey[V + tid] = 0ull;   // pad: 0 never > any valid key
  __syncthreads();

  // ---- rank = count of (valid) keys greater, 4-way unrolled ----
  int Vr = (V + 3) & ~3;
  int r = 0;
  for (int s = 0; s < Vr; s += 4) {
    u64 a0 = ckey[s], a1 = ckey[s + 1], a2 = ckey[s + 2], a3 = ckey[s + 3];
    r += (a0 > key) ? 1 : 0;
    r += (a1 > key) ? 1 : 0;
    r += (a2 > key) ? 1 : 0;
    r += (a3 > key) ? 1 : 0;
  }

  // ---- scatter valid entries to sorted slots ----
  if (valid) {
    int so = g * P_ + r;
    scsS[so] = v;
    ((float4*)ptsS)[so * 2]     = make_float4(X[0], X[1], X[2], X[3]);
    ((float4*)ptsS)[so * 2 + 1] = make_float4(Y[0], Y[1], Y[2], Y[3]);
    ((float4*)aabbS)[so] = make_float4(minx, miny, maxx, maxy);
    pr5S[so * 5 + 0] = px; pr5S[so * 5 + 1] = py;
    pr5S[so * 5 + 2] = pw; pr5S[so * 5 + 3] = ph;
    pr5S[so * 5 + 4] = pa;
    areaS[so] = area;
  }
  if (tid == 0) gV[g] = V;
}

// ---------------------------------------------------------------------------
// exact convex quad-quad intersection area — register-resident, bit-identical
// float op order vs reference (fp contract off). Clips quad q by edges of r.
// ---------------------------------------------------------------------------
__device__ __forceinline__ float inter_area_reg(const float qx[4], const float qy[4],
                                                const float rx[4], const float ry[4]) {
  float px_[8], py_[8];
  #pragma unroll
  for (int t = 0; t < 8; ++t) { px_[t] = (t < 4) ? qx[t] : 0.f; py_[t] = (t < 4) ? qy[t] : 0.f; }
  int n = 4;
  #pragma unroll
  for (int e = 0; e < 4; ++e) {
    float a0 = rx[e], a1 = ry[e];
    float b0 = rx[(e + 1) & 3], b1 = ry[(e + 1) & 3];
    float dx = b0 - a0, dy = b1 - a1;
    float ox_[8], oy_[8];
    #pragma unroll
    for (int t = 0; t < 8; ++t) { ox_[t] = 0.f; oy_[t] = 0.f; }
    float cr[8];
    #pragma unroll
    for (int t = 0; t < 8; ++t) cr[t] = dx * (py_[t] - a1) - dy * (px_[t] - a0);
    int m = 0;
    int nn = (n > 1) ? n : 1;
    #pragma unroll
    for (int t = 0; t < 8; ++t) {
      bool act = t < n;
      float sx = px_[t], sy = py_[t];
      float ex, ey, ce;
      if (t == 7) { ex = px_[0]; ey = py_[0]; ce = cr[0]; }
      else {
        bool wrap = (t + 1 == nn);
        ex = wrap ? px_[0] : px_[t + 1];
        ey = wrap ? py_[0] : py_[t + 1];
        ce = wrap ? cr[0] : cr[t + 1];
      }
      float cs = cr[t];
      float denom = cs - ce;
      float dn = (fabsf(denom) > 1e-12f) ? denom : 1e-12f;
      float tt = cs / dn;
      float ipx = sx + tt * (ex - sx);
      float ipy = sy + tt * (ey - sy);
      bool s_in = cs >= 0.f, e_in = ce >= 0.f;
      bool app1 = act && (s_in != e_in);
      #pragma unroll
      for (int s2 = 0; s2 < 8; ++s2) {
        bool wr = app1 && (m == s2);
        ox_[s2] = wr ? ipx : ox_[s2];
        oy_[s2] = wr ? ipy : oy_[s2];
      }
      m += app1 ? 1 : 0;
      bool app2 = act && e_in;
      #pragma unroll
      for (int s2 = 0; s2 < 8; ++s2) {
        bool wr = app2 && (m == s2);
        ox_[s2] = wr ? ex : ox_[s2];
        oy_[s2] = wr ? ey : oy_[s2];
      }
      m += app2 ? 1 : 0;
    }
    n = m;
    #pragma unroll
    for (int t = 0; t < 8; ++t) { px_[t] = ox_[t]; py_[t] = oy_[t]; }
  }
  int nn = (n > 1) ? n : 1;
  float s = 0.f;
  #pragma unroll
  for (int t = 0; t < 8; ++t) {
    if (t < n) {
      float nx_x, nx_y;
      if (t == 7) { nx_x = px_[0]; nx_y = py_[0]; }
      else {
        bool wrap = (t + 1 == nn);
        nx_x = wrap ? px_[0] : px_[t + 1];
        nx_y = wrap ? py_[0] : py_[t + 1];
      }
      s += px_[t] * nx_y - nx_x * py_[t];
    }
  }
  float area = 0.5f * fabsf(s);
  return (n >= 3) ? area : 0.f;
}

// ---------------------------------------------------------------------------
// K2 (pair): AABB-filter + LDS-compact + dense IoU over surviving pairs.
// grid = (128, 40); 256 thr x 4 pair-slots = 1024 pairs/block.
// ---------------------------------------------------------------------------
#define PPT 4
#define TPB 256
__global__ void pair_kernel(const int* __restrict__ gV,
                            const float* __restrict__ aabbS,
                            const float* __restrict__ areaS,
                            const float* __restrict__ ptsS,
                            u64* __restrict__ sup) {
  int g = blockIdx.y;
  int V = gV[g];
  int Tp = V * (V - 1) / 2;
  int base = blockIdx.x * (TPB * PPT);
  if (base >= Tp) return;
  __shared__ u32 q[TPB * PPT];
  __shared__ int qn;
  int tid = threadIdx.x;
  if (tid == 0) qn = 0;
  __syncthreads();
  const float4* ab = (const float4*)aabbS;
  for (int t = 0; t < PPT; ++t) {
    int kk = base + t * TPB + tid;
    if (kk >= Tp) break;
    float kf = (float)kk;
    int i = (int)((1.0f + sqrtf(1.0f + 8.0f * kf)) * 0.5f);
    while (i * (i - 1) / 2 > kk) --i;
    while ((i + 1) * i / 2 <= kk) ++i;
    int j = kk - i * (i - 1) / 2;
    float4 bi = ab[g * P_ + i];
    float4 bj = ab[g * P_ + j];
    bool ov = (bi.x <= bj.z) && (bj.x <= bi.z) && (bi.y <= bj.w) && (bj.y <= bi.w);
    if (ov) {
      int s = atomicAdd(&qn, 1);
      q[s] = (u32)((i << 9) | j);
    }
  }
  __syncthreads();
  int nq = qn;
  const float4* pS = (const float4*)ptsS;
  for (int s = tid; s < nq; s += TPB) {
    u32 pk = q[s];
    int i = (int)(pk >> 9), j = (int)(pk & 511);
    float4 ax = pS[(g * P_ + i) * 2];
    float4 ay = pS[(g * P_ + i) * 2 + 1];
    float4 bx = pS[(g * P_ + j) * 2];
    float4 by = pS[(g * P_ + j) * 2 + 1];
    float qx[4] = {ax.x, ax.y, ax.z, ax.w};
    float qy[4] = {ay.x, ay.y, ay.z, ay.w};
    float rx[4] = {bx.x, bx.y, bx.z, bx.w};
    float ry[4] = {by.x, by.y, by.z, by.w};
    float ai = areaS[g * P_ + i];
    float aj = areaS[g * P_ + j];
    // reference iou[i][j]: clip quad i by edges of quad j
    float inter = inter_area_reg(qx, qy, rx, ry);
    float iou = inter / (((ai + aj) - inter) + 1e-8f);
    if (iou > NMS_THR)
      atomicOr(&sup[((size_t)g * P_ + i) * 8 + (j >> 6)], 1ull << (j & 63));
  }
}

// ---------------------------------------------------------------------------
// K3 (greedy): sequential greedy over bitmask rows with a 4-deep register
// pipeline (rows i+1..i+4 in flight; only keepw is loop-carried) + emit keys
// and 12-float records for the first 100 kept per group.
// ---------------------------------------------------------------------------
__global__ void greedy_kernel(const float* __restrict__ scsS, const int* __restrict__ gV,
                              const float* __restrict__ aabbS, const float* __restrict__ pr5S,
                              const u64* __restrict__ sup,
                              u64* __restrict__ cand, float* __restrict__ rec) {
  int g = blockIdx.x;
  int tid = threadIdx.x;   // 64
  __shared__ u64 lsup[P_ * 8];
  __shared__ u32 skeep[16];
  int V = gV[g];
  for (int w = tid; w < V * 8; w += 64) lsup[w] = sup[(size_t)g * P_ * 8 + w];
  __syncthreads();
  bool act = tid < 8;
  u64 keepw = 0;
  u64 r0 = (act && 0 < V) ? lsup[0 * 8 + tid] : 0ull;
  u64 r1 = (act && 1 < V) ? lsup[1 * 8 + tid] : 0ull;
  u64 r2 = (act && 2 < V) ? lsup[2 * 8 + tid] : 0ull;
  u64 r3 = (act && 3 < V) ? lsup[3 * 8 + tid] : 0ull;
  for (int i = 0; i < V; ++i) {
    u64 nxt = (act && (i + 4) < V) ? lsup[(i + 4) * 8 + tid] : 0ull;  // 4-deep prefetch
    bool supd = __any((r0 & keepw) != 0ull);
    if (!supd && tid == (i >> 6)) keepw |= 1ull << (i & 63);
    r0 = r1; r1 = r2; r2 = r3; r3 = nxt;
  }
  if (tid < 8) { skeep[tid * 2] = (u32)keepw; skeep[tid * 2 + 1] = (u32)(keepw >> 32); }
  __syncthreads();
  int cls = g % CF;
  int tot = 0;
  #pragma unroll
  for (int t = 0; t < 16; ++t) tot += __popc(skeep[t]);
  for (int r = tid; r < V; r += 64) {
    if ((skeep[r >> 5] >> (r & 31)) & 1u) {
      int slot = __popc(skeep[r >> 5] & ((1u << (r & 31)) - 1u));
      for (int t = 0; t < (r >> 5); ++t) slot += __popc(skeep[t]);
      if (slot < DET) {
        float sv = scsS[g * P_ + r];
        int flat = cls * P_ + r;
        cand[g * DET + slot] = ((u64)f2o(sv) << 32) | (u32)(~(u32)flat);
        int so = g * P_ + r;
        float* rr = rec + (size_t)(g * DET + slot) * 12;
        rr[0] = fminf(fmaxf(aabbS[so * 4 + 0], 0.f), 1023.0f);
        rr[1] = fminf(fmaxf(aabbS[so * 4 + 1], 0.f), 799.0f);
        rr[2] = fminf(fmaxf(aabbS[so * 4 + 2], 0.f), 1023.0f);
        rr[3] = fminf(fmaxf(aabbS[so * 4 + 3], 0.f), 799.0f);
        rr[4] = pr5S[so * 5 + 0]; rr[5] = pr5S[so * 5 + 1]; rr[6] = pr5S[so * 5 + 2];
        rr[7] = pr5S[so * 5 + 3]; rr[8] = pr5S[so * 5 + 4];
        rr[9] = sv;
        rr[10] = (float)(cls + 1);
        rr[11] = 0.f;
      }
    }
  }
  int fill = tot < DET ? tot : DET;
  for (int s = fill + tid; s < DET; s += 64) cand[g * DET + s] = 0ull;
}

// ---------------------------------------------------------------------------
// K4 (rank): per-image top-100 by rank (binary search per sorted group list);
// scatter record to row `rank`; zero-fill unused rows in-kernel (no memset).
// out layout: bb[2,100,4] | rr[2,100,5] | sc[2,100] | lab[2,100] (all f32)
// ---------------------------------------------------------------------------
__global__ void rank_kernel(const u64* __restrict__ cand, const float* __restrict__ rec,
                            float* __restrict__ out) {
  int b = blockIdx.y;
  int tid = threadIdx.x;
  __shared__ u64 lc[NC];
  __shared__ int ncand;
  if (tid == 0) ncand = 0;
  __syncthreads();
  int nz = 0;
  for (int i = tid; i < NC; i += 256) {
    u64 v = cand[b * NC + i];
    lc[i] = v;
    nz += (v != 0ull) ? 1 : 0;
  }
  if (nz > 0) atomicAdd(&ncand, nz);
  __syncthreads();
  int ci = blockIdx.x * 256 + tid;
  if (ci >= NC) return;
  // zero-fill unused rows from block 0
  if (blockIdx.x == 0 && tid < DET && tid >= ncand) {
    int o_bb = (b * DET + tid) * 4;
    int o_rr = B_ * DET * 4 + (b * DET + tid) * 5;
    int o_sc = B_ * DET * 9 + b * DET + tid;
    int o_lab = B_ * DET * 10 + b * DET + tid;
    out[o_bb + 0] = 0.f; out[o_bb + 1] = 0.f; out[o_bb + 2] = 0.f; out[o_bb + 3] = 0.f;
    out[o_rr + 0] = 0.f; out[o_rr + 1] = 0.f; out[o_rr + 2] = 0.f;
    out[o_rr + 3] = 0.f; out[o_rr + 4] = 0.f;
    out[o_sc] = 0.f;
    out[o_lab] = 0.f;
  }
  u64 k = lc[ci];
  if (k == 0ull) return;
  int rank = 0;
  #pragma unroll
  for (int gp = 0; gp < CF; ++gp) {
    int lo = 0, hi = DET;
    while (lo < hi) {            // first idx with lc[gp*DET+idx] <= k (desc list)
      int mid = (lo + hi) >> 1;
      if (lc[gp * DET + mid] > k) lo = mid + 1; else hi = mid;
    }
    rank += lo;
  }
  if (rank >= DET) return;
  const float* rr = rec + (size_t)(b * NC + ci) * 12;
  int o_bb = (b * DET + rank) * 4;
  int o_rr = B_ * DET * 4 + (b * DET + rank) * 5;
  int o_sc = B_ * DET * 9 + b * DET + rank;
  int o_lab = B_ * DET * 10 + b * DET + rank;
  out[o_bb + 0] = rr[0]; out[o_bb + 1] = rr[1];
  out[o_bb + 2] = rr[2]; out[o_bb + 3] = rr[3];
  out[o_rr + 0] = rr[4]; out[o_rr + 1] = rr[5]; out[o_rr + 2] = rr[6];
  out[o_rr + 3] = rr[7]; out[o_rr + 4] = rr[8];
  out[o_sc] = rr[9];
  out[o_lab] = rr[10];
}

// ---------------------------------------------------------------------------
extern "C" void kernel_launch(void* const* d_in, const int* in_sizes, int n_in,
                              void* d_out, int out_size, void* d_ws, size_t ws_size,
                              hipStream_t stream) {
  const float* logits = (const float*)d_in[0];
  const float* breg   = (const float*)d_in[1];
  const float* rrects = (const float*)d_in[2];
  float* out = (float*)d_out;

  const int G = B_ * CF;
  u64*   sup  = (u64*)d_ws;                          // G*P*8 u64 = 1.31 MB
  u64*   cand = sup + (size_t)G * P_ * 8;            // G*DET u64
  int*   gV   = (int*)(cand + G * DET);              // 64 ints (padded)
  float* scsS = (float*)(gV + 64);                   // G*P
  float* ptsS = scsS + (size_t)G * P_;               // G*P*8
  float* aabbS = ptsS + (size_t)G * P_ * 8;          // G*P*4
  float* pr5S = aabbS + (size_t)G * P_ * 4;          // G*P*5
  float* areaS = pr5S + (size_t)G * P_ * 5;          // G*P
  float* rec  = areaS + (size_t)G * P_;              // G*DET*12

  prep_kernel<<<G, 512, 0, stream>>>(logits, breg, rrects,
                                     scsS, ptsS, aabbS, pr5S, areaS, gV, sup);
  pair_kernel<<<dim3(128, G), TPB, 0, stream>>>(gV, aabbS, areaS, ptsS, sup);
  greedy_kernel<<<G, 64, 0, stream>>>(scsS, gV, aabbS, pr5S, sup, cand, rec);
  rank_kernel<<<dim3((NC + 255) / 256, B_), 256, 0, stream>>>(cand, rec, out);
}